// Round 1
// baseline (65.772 us; speedup 1.0000x reference)
//
#include <hip/hip_runtime.h>
#include <math.h>

#define NB 512
#define NK 64
#define NP 25
#define HW 400
#define NC 10

__global__ __launch_bounds__(256) void geneo_mlp_kernel(
    const float* __restrict__ x,        // (B,1,20,20)
    const float* __restrict__ patterns, // (K,1,5,5)
    const float* __restrict__ w2,       // (1,K)
    const float* __restrict__ b2,       // (1,)
    const float* __restrict__ wf,       // (NC,400)
    const float* __restrict__ bf,       // (NC,)
    float* __restrict__ out)            // (B,NC)
{
    __shared__ float xp[24 * 24];
    __shared__ float pat[NK * NP];
    __shared__ float w2s[NK];
    __shared__ float redv[NK][4];
    __shared__ int   redi[NK][4];
    __shared__ float contribV[NK];
    __shared__ int   contribI[NK];
    __shared__ float wsum[4][NC];

    const int tid  = threadIdx.x;
    const int b    = blockIdx.x;
    const int lane = tid & 63;
    const int wave = tid >> 6;

    // ---- stage padded image (pad=2 each side, 24x24) ----
    for (int i = tid; i < 24 * 24; i += 256) {
        int h = i / 24, w = i % 24;
        float v = 0.f;
        if (h >= 2 && h < 22 && w >= 2 && w < 22)
            v = x[b * HW + (h - 2) * 20 + (w - 2)];
        xp[i] = v;
    }
    // ---- stage patterns + w2 ----
    for (int i = tid; i < NK * NP; i += 256) pat[i] = patterns[i];
    if (tid < NK) w2s[tid] = w2[tid];
    __syncthreads();

    // ---- each thread owns pixel p0 = tid, and p1 = tid+256 (if < 400) ----
    const int  p0   = tid;
    const int  p1v  = tid + 256;
    const bool has1 = (p1v < HW);
    const int  p1   = has1 ? p1v : 0;

    float patch0[NP], patch1[NP];
    {
        const int h0 = p0 / 20, w0 = p0 % 20;
        const int h1 = p1 / 20, w1 = p1 % 20;
        #pragma unroll
        for (int j = 0; j < NP; ++j) {
            const int dy = j / 5, dx = j % 5;
            patch0[j] = xp[(h0 + dy) * 24 + (w0 + dx)];
            patch1[j] = xp[(h1 + dy) * 24 + (w1 + dx)];
        }
    }

    // ---- per-k: F = 1 - mean|pat - patch|, block argmax (first occurrence) ----
    for (int k = 0; k < NK; ++k) {
        float s0 = 0.f, s1 = 0.f;
        #pragma unroll
        for (int j = 0; j < NP; ++j) {
            const float pv = pat[k * NP + j];
            s0 += fabsf(pv - patch0[j]);
            s1 += fabsf(pv - patch1[j]);
        }
        float bv = 1.f - s0 * (1.f / 25.f);
        int   bi = p0;
        const float F1 = has1 ? (1.f - s1 * (1.f / 25.f)) : -1e30f;
        if (F1 > bv) { bv = F1; bi = p1v; }   // p0 < p1v: tie keeps p0

        #pragma unroll
        for (int off = 32; off >= 1; off >>= 1) {
            const float ov = __shfl_down(bv, off);
            const int   oi = __shfl_down(bi, off);
            if (ov > bv || (ov == bv && oi < bi)) { bv = ov; bi = oi; }
        }
        if (lane == 0) { redv[k][wave] = bv; redi[k][wave] = bi; }
    }
    __syncthreads();

    // ---- combine 4 wave partials per k; contribution = max * w2[k] ----
    if (tid < NK) {
        float bv = redv[tid][0];
        int   bi = redi[tid][0];
        #pragma unroll
        for (int wv = 1; wv < 4; ++wv) {
            const float ov = redv[tid][wv];
            const int   oi = redi[tid][wv];
            if (ov > bv || (ov == bv && oi < bi)) { bv = ov; bi = oi; }
        }
        contribV[tid] = bv * w2s[tid];
        contribI[tid] = bi;
    }
    __syncthreads();

    // ---- t = sigmoid(scatter + b2) at this thread's pixels; partial 400->10 dot ----
    float acc[NC];
    #pragma unroll
    for (int c = 0; c < NC; ++c) acc[c] = 0.f;
    const float b2v = b2[0];

    {
        float s = b2v;
        for (int k = 0; k < NK; ++k)
            if (contribI[k] == p0) s += contribV[k];
        const float t = 1.f / (1.f + expf(-s));
        #pragma unroll
        for (int c = 0; c < NC; ++c) acc[c] += t * wf[c * HW + p0];
    }
    if (has1) {
        float s = b2v;
        for (int k = 0; k < NK; ++k)
            if (contribI[k] == p1v) s += contribV[k];
        const float t = 1.f / (1.f + expf(-s));
        #pragma unroll
        for (int c = 0; c < NC; ++c) acc[c] += t * wf[c * HW + p1v];
    }

    // ---- block reduce the 10 class sums ----
    #pragma unroll
    for (int c = 0; c < NC; ++c) {
        #pragma unroll
        for (int off = 32; off >= 1; off >>= 1)
            acc[c] += __shfl_down(acc[c], off);
    }
    if (lane == 0) {
        #pragma unroll
        for (int c = 0; c < NC; ++c) wsum[wave][c] = acc[c];
    }
    __syncthreads();
    if (tid < NC) {
        const float s = wsum[0][tid] + wsum[1][tid] + wsum[2][tid] + wsum[3][tid] + bf[tid];
        out[b * NC + tid] = 1.f / (1.f + expf(-s));
    }
}

extern "C" void kernel_launch(void* const* d_in, const int* in_sizes, int n_in,
                              void* d_out, int out_size, void* d_ws, size_t ws_size,
                              hipStream_t stream) {
    const float* x        = (const float*)d_in[0];
    const float* patterns = (const float*)d_in[1];
    const float* w2       = (const float*)d_in[2];
    const float* b2       = (const float*)d_in[3];
    const float* wf       = (const float*)d_in[4];
    const float* bf       = (const float*)d_in[5];
    float* out = (float*)d_out;

    geneo_mlp_kernel<<<NB, 256, 0, stream>>>(x, patterns, w2, b2, wf, bf, out);
}

// Round 2
// 20.519 us; speedup vs baseline: 3.2055x; 3.2055x over previous
//
#include <hip/hip_runtime.h>
#include <math.h>

#define NB 512
#define NK 64
#define NP 25
#define HW 400
#define NC 10
#define NWAVE 4
#define RPW 5   // rows per wave

__global__ __launch_bounds__(256) void geneo_mlp_kernel(
    const float* __restrict__ x,        // (B,1,20,20)
    const float* __restrict__ patterns, // (K,1,5,5)
    const float* __restrict__ w2,       // (1,K)
    const float* __restrict__ b2,       // (1,)
    const float* __restrict__ wf,       // (NC,400)
    const float* __restrict__ bf,       // (NC,)
    float* __restrict__ out)            // (B,NC)
{
    __shared__ __align__(16) float xp[24 * 24];
    __shared__ float  redv[NWAVE][NK];
    __shared__ int    redi[NWAVE][NK];
    __shared__ float2 contrib[NK];      // (value*w2, bitcast idx)
    __shared__ float  wsum[NWAVE][NC];

    const int tid  = threadIdx.x;
    const int b    = blockIdx.x;
    const int lane = tid & 63;
    const int wave = tid >> 6;

    // ---- stage padded image (pad=2, 24x24, row stride 24 floats = 96B) ----
    for (int i = tid; i < 24 * 24; i += 256) {
        const int h = i / 24, w = i % 24;
        float v = 0.f;
        if (h >= 2 && h < 22 && w >= 2 && w < 22)
            v = x[b * HW + (h - 2) * 20 + (w - 2)];
        xp[i] = v;
    }

    // ---- this lane owns pattern k = lane: 25 values in registers ----
    float patv[NP];
    #pragma unroll
    for (int j = 0; j < NP; ++j) patv[j] = patterns[lane * NP + j];
    __syncthreads();

    // ---- each wave: 5 output rows, all 64 k in parallel (lane = k) ----
    float bv = -1e30f;
    int   bi = 0;

    #pragma unroll 1
    for (int r = 0; r < RPW; ++r) {
        const int h = wave * RPW + r;

        // sliding window: 5 input rows x 8 cols, wave-uniform values
        float Wn[5][8];
        #pragma unroll
        for (int q = 0; q < 5; ++q) {
            const float4 a = *reinterpret_cast<const float4*>(&xp[(h + q) * 24 + 0]);
            const float4 c = *reinterpret_cast<const float4*>(&xp[(h + q) * 24 + 4]);
            Wn[q][0] = a.x; Wn[q][1] = a.y; Wn[q][2] = a.z; Wn[q][3] = a.w;
            Wn[q][4] = c.x; Wn[q][5] = c.y; Wn[q][6] = c.z; Wn[q][7] = c.w;
        }

        #pragma unroll
        for (int cb = 0; cb < 5; ++cb) {           // 5 col-blocks of 4 pixels
            #pragma unroll
            for (int px = 0; px < 4; ++px) {
                float s = 0.f;
                #pragma unroll
                for (int dy = 0; dy < 5; ++dy)
                    #pragma unroll
                    for (int dx = 0; dx < 5; ++dx)
                        s += fabsf(patv[dy * 5 + dx] - Wn[dy][px + dx]);
                const float F = 1.f - s * (1.f / 25.f);
                const int   p = h * 20 + cb * 4 + px;
                if (F > bv) { bv = F; bi = p; }    // strict >: first occurrence
            }
            if (cb < 4) {                          // shift window left by 4, load 4 new cols
                #pragma unroll
                for (int q = 0; q < 5; ++q) {
                    Wn[q][0] = Wn[q][4]; Wn[q][1] = Wn[q][5];
                    Wn[q][2] = Wn[q][6]; Wn[q][3] = Wn[q][7];
                    const float4 nb = *reinterpret_cast<const float4*>(
                        &xp[(h + q) * 24 + cb * 4 + 8]);
                    Wn[q][4] = nb.x; Wn[q][5] = nb.y; Wn[q][6] = nb.z; Wn[q][7] = nb.w;
                }
            }
        }
    }
    redv[wave][lane] = bv;
    redi[wave][lane] = bi;
    __syncthreads();

    // ---- combine 4 wave partials (waves ordered by pixel index -> strict >) ----
    if (tid < NK) {
        float v0 = redv[0][tid];
        int   i0 = redi[0][tid];
        #pragma unroll
        for (int w = 1; w < NWAVE; ++w) {
            const float ov = redv[w][tid];
            const int   oi = redi[w][tid];
            if (ov > v0) { v0 = ov; i0 = oi; }
        }
        contrib[tid] = make_float2(v0 * w2[tid], __int_as_float(i0));
    }
    __syncthreads();

    // ---- sigmoid(scatter + b2) at owned pixels; partial 400->10 dot ----
    float acc[NC];
    #pragma unroll
    for (int c = 0; c < NC; ++c) acc[c] = 0.f;
    const float b2v = b2[0];

    {
        const int p0 = tid;
        float s = b2v;
        for (int k = 0; k < NK; ++k) {
            const float2 cv = contrib[k];
            if (__float_as_int(cv.y) == p0) s += cv.x;
        }
        const float t = 1.f / (1.f + expf(-s));
        #pragma unroll
        for (int c = 0; c < NC; ++c) acc[c] += t * wf[c * HW + p0];
    }
    if (tid + 256 < HW) {
        const int p1 = tid + 256;
        float s = b2v;
        for (int k = 0; k < NK; ++k) {
            const float2 cv = contrib[k];
            if (__float_as_int(cv.y) == p1) s += cv.x;
        }
        const float t = 1.f / (1.f + expf(-s));
        #pragma unroll
        for (int c = 0; c < NC; ++c) acc[c] += t * wf[c * HW + p1];
    }

    // ---- block-reduce the 10 class sums ----
    #pragma unroll
    for (int c = 0; c < NC; ++c) {
        #pragma unroll
        for (int off = 32; off >= 1; off >>= 1)
            acc[c] += __shfl_down(acc[c], off);
    }
    if (lane == 0) {
        #pragma unroll
        for (int c = 0; c < NC; ++c) wsum[wave][c] = acc[c];
    }
    __syncthreads();
    if (tid < NC) {
        const float s = wsum[0][tid] + wsum[1][tid] + wsum[2][tid] + wsum[3][tid] + bf[tid];
        out[b * NC + tid] = 1.f / (1.f + expf(-s));
    }
}

extern "C" void kernel_launch(void* const* d_in, const int* in_sizes, int n_in,
                              void* d_out, int out_size, void* d_ws, size_t ws_size,
                              hipStream_t stream) {
    const float* x        = (const float*)d_in[0];
    const float* patterns = (const float*)d_in[1];
    const float* w2       = (const float*)d_in[2];
    const float* b2       = (const float*)d_in[3];
    const float* wf       = (const float*)d_in[4];
    const float* bf       = (const float*)d_in[5];
    float* out = (float*)d_out;

    geneo_mlp_kernel<<<NB, 256, 0, stream>>>(x, patterns, w2, b2, wf, bf, out);
}